// Round 13
// baseline (476.279 us; speedup 1.0000x reference)
//
#include <hip/hip_runtime.h>
#include <hip/hip_bf16.h>

typedef unsigned short u16;
typedef unsigned int u32;
typedef unsigned long long u64;
typedef __bf16 bf16x8 __attribute__((ext_vector_type(8)));
typedef float f32x4 __attribute__((ext_vector_type(4)));
typedef u16 u16x8 __attribute__((ext_vector_type(8)));

#define B_ 2
#define S_ 2048
#define NH 32
#define NKV 8
#define HD 128
#define DIM_ 4096
#define NQKV 6144  // fused projection width: 4096 Q + 1024 K + 1024 V

__device__ inline u16 f2b(float f) {
  u32 u = __builtin_bit_cast(u32, f);
  u = (u + 0x7fffu + ((u >> 16) & 1u)) >> 16;
  return (u16)u;
}
__device__ inline float b2f(u16 b) {
  u32 u = ((u32)b) << 16;
  return __builtin_bit_cast(float, u);
}

__device__ inline void gload_lds16(const u16* g, u16* l) {
  __builtin_amdgcn_global_load_lds((__attribute__((address_space(1))) void*)g,
                                   (__attribute__((address_space(3))) void*)l, 16, 0, 0);
}

#define BARRIER_()                      \
  __builtin_amdgcn_sched_barrier(0);    \
  __builtin_amdgcn_s_barrier();         \
  __builtin_amdgcn_sched_barrier(0)

#define VM(N) asm volatile("s_waitcnt vmcnt(" #N ")" ::: "memory")
#define NOP_ ((void)0)

// ------- merged f32 -> bf16 cast (5 tensors) + (cos,sin) float2 table build -------
__global__ __launch_bounds__(256) void k_cast_all(const float* __restrict__ x,
                                                  const float* __restrict__ wq,
                                                  const float* __restrict__ wk,
                                                  const float* __restrict__ wv,
                                                  const float* __restrict__ wo,
                                                  const float* __restrict__ cosb,
                                                  const float* __restrict__ sinb,
                                                  u16* __restrict__ xb,
                                                  u16* __restrict__ wqkvb,
                                                  u16* __restrict__ wob,
                                                  float2* __restrict__ cs) {
  int i = blockIdx.x * 256 + threadIdx.x;
  if (i >= 14680064) {  // cs table: 2048*64 entries
    const int idx = i - 14680064;
    cs[idx] = make_float2(cosb[idx], sinb[idx]);
    return;
  }
  const float* s;
  u16* d;
  int j;
  if (i < 4194304) { s = x; d = xb; j = i; }
  else if (i < 8388608) { s = wq; d = wqkvb; j = i - 4194304; }
  else if (i < 9437184) { s = wk; d = wqkvb + (size_t)4096 * 4096; j = i - 8388608; }
  else if (i < 10485760) { s = wv; d = wqkvb + (size_t)5120 * 4096; j = i - 9437184; }
  else { s = wo; d = wob; j = i - 10485760; }
  const float4 v = ((const float4*)s)[j];
  u32 lo = (u32)f2b(v.x) | ((u32)f2b(v.y) << 16);
  u32 hi = (u32)f2b(v.z) | ((u32)f2b(v.w) << 16);
  ((u32*)d)[(size_t)j * 2] = lo;
  ((u32*)d)[(size_t)j * 2 + 1] = hi;
}

// ========== 128x192 QKV GEMM, 4 waves, 2 blocks/CU (LDS=80KB), fused RoPE ==========
// 1-barrier dbuf schedule: stage t+1 -> buf^1, read frags buf, MFMA, VM(0), barrier.
// Two desync'd blocks per CU hide each other's drains (m114 overlap).
// Groups: A0,A1 (rows 0-127) = lds[.][0..1]; B0..2 (cols 0-191) = lds[.][2..4].
template <int K, int MT, int NT, int CM, int CN>
__global__ __launch_bounds__(256, 2) void k_gemm192nf(const u16* __restrict__ A,
                                                      const u16* __restrict__ Bm,
                                                      u16* __restrict__ Q,
                                                      u16* __restrict__ Kr,
                                                      u16* __restrict__ Vt,
                                                      const float2* __restrict__ cs) {
  __shared__ __align__(16) u16 lds[2][5][64 * 64];  // 80KB exactly -> 2 blocks/CU
  const int bid = blockIdx.x;
  const int xcd = bid & 7, slot = bid >> 3;
  constexpr int XM = MT / CM;  // 4
  const int xm = xcd % XM, xn = xcd / XM;
  const int m0 = (xm * CM + slot % CM) * 128;
  const int n0 = (xn * CN + slot / CM) * 192;
  const int tid = threadIdx.x, w = tid >> 6, lane = tid & 63;
  const int wn = w;  // 1m x 4n wave grid: each wave = 128 rows x 48 cols
  const int lr = lane & 15, lg = lane >> 4;
  const int lrow8 = lane >> 3;
  const int gcol = ((lane & 7) ^ lrow8) * 8;  // pre-swizzled source k-col (u16)
  f32x4 acc[8][3] = {};
  const u16* gsrc[5];
#pragma unroll
  for (int g = 0; g < 2; ++g) gsrc[g] = A + (size_t)(m0 + g * 64) * K;
#pragma unroll
  for (int g = 0; g < 3; ++g) gsrc[2 + g] = Bm + (size_t)(n0 + g * 64) * K;

#define SG(DST, G, I, KN)                                                           \
  gload_lds16(gsrc[G] + (size_t)(w * 16 + (I) * 8 + lrow8) * K + (KN) + gcol,       \
              &lds[DST][G][(w * 16 + (I) * 8) * 64])

#define TILE1B(BB, HS, KN, LAST)                                                    \
  {                                                                                 \
    if (HS) {                                                                       \
      SG(BB ^ 1, 0, 0, KN); SG(BB ^ 1, 0, 1, KN);                                   \
      SG(BB ^ 1, 1, 0, KN); SG(BB ^ 1, 1, 1, KN);                                   \
      SG(BB ^ 1, 2, 0, KN); SG(BB ^ 1, 2, 1, KN);                                   \
      SG(BB ^ 1, 3, 0, KN); SG(BB ^ 1, 3, 1, KN);                                   \
      SG(BB ^ 1, 4, 0, KN); SG(BB ^ 1, 4, 1, KN);                                   \
    }                                                                               \
    bf16x8 af[8][2];                                                                \
    _Pragma("unroll") for (int f = 0; f < 8; ++f)                                   \
      _Pragma("unroll") for (int ks = 0; ks < 2; ++ks)                              \
        af[f][ks] = *(const bf16x8*)&lds[BB][f >> 2]                                \
            [((f & 3) * 16 + lr) * 64 + (((ks * 4 + lg) ^ (lr & 7)) * 8)];          \
    __builtin_amdgcn_s_setprio(1);                                                  \
    _Pragma("unroll") for (int nf = 0; nf < 3; ++nf) {                              \
      const int bcol = wn * 48 + nf * 16;                                           \
      bf16x8 bfr[2];                                                                \
      _Pragma("unroll") for (int ks = 0; ks < 2; ++ks)                              \
        bfr[ks] = *(const bf16x8*)&lds[BB][2 + (bcol >> 6)]                         \
            [((bcol & 63) + lr) * 64 + (((ks * 4 + lg) ^ (lr & 7)) * 8)];           \
      _Pragma("unroll") for (int f = 0; f < 8; ++f)                                 \
        _Pragma("unroll") for (int ks = 0; ks < 2; ++ks)                            \
          acc[f][nf] = __builtin_amdgcn_mfma_f32_16x16x32_bf16(af[f][ks], bfr[ks],  \
                                                              acc[f][nf], 0, 0, 0);\
    }                                                                               \
    __builtin_amdgcn_s_setprio(0);                                                  \
    if (LAST) { VM(0); BARRIER_(); }                                                \
  }

  // prologue: stage tile 0 -> buf0, full drain
#pragma unroll
  for (int g = 0; g < 5; ++g) { SG(0, g, 0, 0); SG(0, g, 1, 0); }
  VM(0);
  BARRIER_();

  for (int tt = 0; tt < (K / 64) - 2; tt += 2) {
    TILE1B(0, 1, (tt + 1) * 64, 1);
    TILE1B(1, 1, (tt + 2) * 64, 1);
  }
  TILE1B(0, 1, (K / 64 - 1) * 64, 1);  // stages final tile
  TILE1B(1, 0, 0, 0);                  // final tile: pure compute, no sync
#undef TILE1B
#undef SG

  // -------- fused RoPE + layout epilogue --------
#pragma unroll
  for (int f = 0; f < 8; ++f) {
    const int r = m0 + f * 16 + lg * 4;
    const int b = r >> 11;   // rows r..r+3 share b
    const int s = r & 2047;
#pragma unroll
    for (int nf = 0; nf < 3; ++nf) {
      const int base = n0 + wn * 48 + nf * 16;  // 16-aligned; Q/K/V boundaries 16-aligned
      const int cc = base + lr;
      if (base < 5120) {  // Q or K: RoPE + [B][H][S][D]
        const bool isQ = base < 4096;
        const int cx = isQ ? cc : cc - 4096;
        const int h = cx >> 7, d = cx & 127;
        u16* dst = (isQ ? Q : Kr) +
                   (((size_t)b * (isQ ? NH : NKV) + h) * S_ + s) * HD + d;
        const float sgn = (lr & 1) ? 1.f : -1.f;
#pragma unroll
        for (int j = 0; j < 4; ++j) {
          const float val = acc[f][nf][j];
          const float par = __shfl_xor(val, 1);
          const float2 csv = cs[(s + j) * 64 + (d >> 1)];
          dst[(size_t)j * HD] = f2b(val * csv.x + sgn * par * csv.y);
        }
      } else {  // V: direct transpose [B][NKV][HD][S], 4 rows packed u64
        const int cv = cc - 5120;
        const int hv = cv >> 7, dv = cv & 127;
        u64 pk = 0;
#pragma unroll
        for (int j = 0; j < 4; ++j)
          pk |= (u64)f2b(acc[f][nf][j]) << (16 * j);
        *(u64*)&Vt[(((size_t)b * NKV + hv) * HD + dv) * S_ + s] = pk;
      }
    }
  }
}

// ========== 128x128 O-projection GEMM (f32 out), 4 waves, 2 blocks/CU ==========
template <int N, int K, int MT, int NT, int CM, int CN>
__global__ __launch_bounds__(256, 2) void k_gemm256(const u16* __restrict__ A,
                                                    const u16* __restrict__ Bm,
                                                    float* __restrict__ Cout) {
  __shared__ __align__(16) u16 lds[2][4][64 * 64];  // 64KB -> 2 blocks/CU
  const int bid = blockIdx.x;
  const int xcd = bid & 7, slot = bid >> 3;
  constexpr int XM = MT / CM;  // 4
  const int xm = xcd % XM, xn = xcd / XM;
  const int m0 = (xm * CM + slot % CM) * 128;
  const int n0 = (xn * CN + slot / CM) * 128;
  const int tid = threadIdx.x, w = tid >> 6, lane = tid & 63;
  const int wn = w;  // 1m x 4n: each wave = 128 rows x 32 cols
  const int lr = lane & 15, lg = lane >> 4;
  const int lrow8 = lane >> 3;
  const int gcol = ((lane & 7) ^ lrow8) * 8;
  f32x4 acc[8][2] = {};
  const u16* gsrc[4];
#pragma unroll
  for (int g = 0; g < 2; ++g) gsrc[g] = A + (size_t)(m0 + g * 64) * K;
#pragma unroll
  for (int g = 0; g < 2; ++g) gsrc[2 + g] = Bm + (size_t)(n0 + g * 64) * K;

#define SG(DST, G, I, KN)                                                           \
  gload_lds16(gsrc[G] + (size_t)(w * 16 + (I) * 8 + lrow8) * K + (KN) + gcol,       \
              &lds[DST][G][(w * 16 + (I) * 8) * 64])

#define TILE1B(BB, HS, KN, LAST)                                                    \
  {                                                                                 \
    if (HS) {                                                                       \
      SG(BB ^ 1, 0, 0, KN); SG(BB ^ 1, 0, 1, KN);                                   \
      SG(BB ^ 1, 1, 0, KN); SG(BB ^ 1, 1, 1, KN);                                   \
      SG(BB ^ 1, 2, 0, KN); SG(BB ^ 1, 2, 1, KN);                                   \
      SG(BB ^ 1, 3, 0, KN); SG(BB ^ 1, 3, 1, KN);                                   \
    }                                                                               \
    bf16x8 af[8][2];                                                                \
    _Pragma("unroll") for (int f = 0; f < 8; ++f)                                   \
      _Pragma("unroll") for (int ks = 0; ks < 2; ++ks)                              \
        af[f][ks] = *(const bf16x8*)&lds[BB][f >> 2]                                \
            [((f & 3) * 16 + lr) * 64 + (((ks * 4 + lg) ^ (lr & 7)) * 8)];          \
    __builtin_amdgcn_s_setprio(1);                                                  \
    _Pragma("unroll") for (int nf = 0; nf < 2; ++nf) {                              \
      const int bcol = wn * 32 + nf * 16;                                           \
      bf16x8 bfr[2];                                                                \
      _Pragma("unroll") for (int ks = 0; ks < 2; ++ks)                              \
        bfr[ks] = *(const bf16x8*)&lds[BB][2 + (bcol >> 6)]                         \
            [((bcol & 63) + lr) * 64 + (((ks * 4 + lg) ^ (lr & 7)) * 8)];           \
      _Pragma("unroll") for (int f = 0; f < 8; ++f)                                 \
        _Pragma("unroll") for (int ks = 0; ks < 2; ++ks)                            \
          acc[f][nf] = __builtin_amdgcn_mfma_f32_16x16x32_bf16(af[f][ks], bfr[ks],  \
                                                              acc[f][nf], 0, 0, 0);\
    }                                                                               \
    __builtin_amdgcn_s_setprio(0);                                                  \
    if (LAST) { VM(0); BARRIER_(); }                                                \
  }

#pragma unroll
  for (int g = 0; g < 4; ++g) { SG(0, g, 0, 0); SG(0, g, 1, 0); }
  VM(0);
  BARRIER_();

  for (int tt = 0; tt < (K / 64) - 2; tt += 2) {
    TILE1B(0, 1, (tt + 1) * 64, 1);
    TILE1B(1, 1, (tt + 2) * 64, 1);
  }
  TILE1B(0, 1, (K / 64 - 1) * 64, 1);
  TILE1B(1, 0, 0, 0);
#undef TILE1B
#undef SG

#pragma unroll
  for (int f = 0; f < 8; ++f) {
    const int r = m0 + f * 16 + lg * 4;
#pragma unroll
    for (int nf = 0; nf < 2; ++nf) {
      const int cc = n0 + wn * 32 + nf * 16 + lr;
#pragma unroll
      for (int j = 0; j < 4; ++j)
        Cout[(size_t)(r + j) * N + cc] = acc[f][nf][j];
    }
  }
}

// ---------------- Flash attention, causal, GQA rep=4 (unchanged from r12) ----------------
__global__ __launch_bounds__(256, 2) void k_attn(const u16* __restrict__ Qg,
                                                 const u16* __restrict__ Kg,
                                                 const u16* __restrict__ Vtg,
                                                 u16* __restrict__ Og) {
  __shared__ __align__(16) u16 Ks[2][64 * 128];   // 2 x 16KB, rows 256B, XOR-swizzled
  __shared__ __align__(16) u16 Vs[2][128 * 64];   // 2 x 16KB, rows 128B, XOR-swizzled
  __shared__ __align__(16) u16 Ps[4][2][16][64];  // 16KB, per-(wave,frag), chunk-swizzled
  const int bid = blockIdx.x;
  const int xcd = bid & 7, slot = bid >> 3;     // grid 1024: 8 xcd x 128
  const int g = xcd * 2 + (slot >> 6);          // (b,kvh) group 0..15
  const int r_ = slot & 63;
  const int hq = r_ & 3;
  const int qt = 15 - (r_ >> 2);                // longest blocks first
  const int b = g >> 3, kvh = g & 7, h = kvh * 4 + hq;
  const int tid = threadIdx.x, wid = tid >> 6, lane = tid & 63;
  const int lr = lane & 15, lg = lane >> 4;
  const int q0 = qt * 128;
  bf16x8 qf[2][4];
#pragma unroll
  for (int f = 0; f < 2; ++f) {
    const u16* qp = Qg + (((size_t)b * NH + h) * S_ + q0 + wid * 32 + f * 16 + lr) * HD + lg * 8;
#pragma unroll
    for (int ks = 0; ks < 4; ++ks) qf[f][ks] = *(const bf16x8*)(qp + ks * 32);
  }
  f32x4 o[2][8] = {};
  float mrun[2] = {-1e30f, -1e30f}, lrun[2] = {0.f, 0.f};
  const u16* kb2 = Kg + ((size_t)b * NKV + kvh) * (size_t)S_ * HD;
  const u16* vb2 = Vtg + ((size_t)b * NKV + kvh) * (size_t)HD * S_;

#define STAGE_KV(BUF, T)                                                               \
  {                                                                                    \
    _Pragma("unroll") for (int i = 0; i < 4; ++i) {                                    \
      const int kr = wid * 16 + i * 4 + lg;                                            \
      gload_lds16(kb2 + (size_t)((T) * 64 + kr) * HD + ((lane & 15) ^ (kr & 7)) * 8,   \
                  &Ks[BUF][(wid * 16 + i * 4) * 128]);                                 \
    }                                                                                  \
    _Pragma("unroll") for (int i = 0; i < 4; ++i) {                                    \
      const int dr = wid * 32 + i * 8 + (lane >> 3);                                   \
      gload_lds16(vb2 + (size_t)dr * S_ + (T) * 64 + ((lane & 7) ^ (dr & 7)) * 8,      \
                  &Vs[BUF][(wid * 32 + i * 8) * 64]);                                  \
    }                                                                                  \
  }

  const int nt = 2 * qt + 2;
  STAGE_KV(0, 0);
  VM(0);
  BARRIER_();
  int cur = 0;
  const int qrow0 = q0 + wid * 32 + lr;
  const int pbase = lr * 16 + (lg & 1);
  for (int t = 0; t < nt; ++t) {
    if (t < nt - 1) STAGE_KV(cur ^ 1, t + 1);
    __builtin_amdgcn_sched_barrier(0);
    const char* KsB = (const char*)&Ks[cur][0];
    const char* VsB = (const char*)&Vs[cur][0];
    f32x4 s[2][4] = {};
    __builtin_amdgcn_s_setprio(1);
#pragma unroll
    for (int ks = 0; ks < 4; ++ks) {
      bf16x8 kf4[4];
#pragma unroll
      for (int n = 0; n < 4; ++n) {
        const int rr = n * 16 + lr;
        kf4[n] = *(const bf16x8*)(KsB + rr * 256 + ((ks * 64 + lg * 16) ^ ((rr & 7) << 4)));
      }
#pragma unroll
      for (int f = 0; f < 2; ++f)
#pragma unroll
        for (int n = 0; n < 4; ++n)
          s[f][n] = __builtin_amdgcn_mfma_f32_16x16x32_bf16(kf4[n], qf[f][ks], s[f][n], 0, 0, 0);
    }
    __builtin_amdgcn_s_setprio(0);
    const float scale = 0.08838834764831845f;
    float pm[2] = {-1e30f, -1e30f};
    const int kvb = t * 64 + lg * 4;
#pragma unroll
    for (int f = 0; f < 2; ++f) {
      const bool diag = (t * 64 + 63 > q0 + wid * 32 + f * 16);
#pragma unroll
      for (int n = 0; n < 4; ++n)
#pragma unroll
        for (int j = 0; j < 4; ++j) {
          float v = s[f][n][j] * scale;
          if (diag && (kvb + n * 16 + j > qrow0 + f * 16)) v = -1e30f;  // causal
          s[f][n][j] = v;
          pm[f] = fmaxf(pm[f], v);
        }
    }
#pragma unroll
    for (int f = 0; f < 2; ++f) {
      pm[f] = fmaxf(pm[f], __shfl_xor(pm[f], 16));
      pm[f] = fmaxf(pm[f], __shfl_xor(pm[f], 32));
    }
    float al[2] = {1.f, 1.f};
    float mt[2] = {mrun[0], mrun[1]};
    if (!__all(pm[0] <= mrun[0] + 8.f && pm[1] <= mrun[1] + 8.f)) {
#pragma unroll
      for (int f = 0; f < 2; ++f) {
        mt[f] = fmaxf(mrun[f], pm[f]);
        al[f] = __expf(mrun[f] - mt[f]);
        mrun[f] = mt[f];
        float alj[4];
#pragma unroll
        for (int j = 0; j < 4; ++j) alj[j] = __shfl(al[f], lg * 4 + j);
#pragma unroll
        for (int c = 0; c < 8; ++c)
#pragma unroll
          for (int j = 0; j < 4; ++j) o[f][c][j] *= alj[j];
      }
    }
    float ls[2] = {0.f, 0.f};
#pragma unroll
    for (int f = 0; f < 2; ++f) {
      u64* Ps64 = (u64*)&Ps[wid][f][0][0];
#pragma unroll
      for (int n = 0; n < 4; ++n) {
        const float p0 = __expf(s[f][n][0] - mt[f]), p1 = __expf(s[f][n][1] - mt[f]);
        const float p2 = __expf(s[f][n][2] - mt[f]), p3 = __expf(s[f][n][3] - mt[f]);
        ls[f] += (p0 + p1) + (p2 + p3);
        const u32 w0 = (u32)f2b(p0) | ((u32)f2b(p1) << 16);
        const u32 w1 = (u32)f2b(p2) | ((u32)f2b(p3) << 16);
        Ps64[pbase + (((n * 2 + (lg >> 1)) ^ (lr & 7)) << 1)] = (u64)w0 | ((u64)w1 << 32);
      }
    }
#pragma unroll
    for (int f = 0; f < 2; ++f) {
      ls[f] += __shfl_xor(ls[f], 16);
      ls[f] += __shfl_xor(ls[f], 32);
      lrun[f] = lrun[f] * al[f] + ls[f];
    }
    asm volatile("s_waitcnt lgkmcnt(0)" ::: "memory");
    __builtin_amdgcn_sched_barrier(0);
    __builtin_amdgcn_s_setprio(1);
#pragma unroll
    for (int ks = 0; ks < 2; ++ks) {
      bf16x8 af0 = *(const bf16x8*)&Ps[wid][0][lr][((ks * 4 + lg) ^ (lr & 7)) * 8];
      bf16x8 af1 = *(const bf16x8*)&Ps[wid][1][lr][((ks * 4 + lg) ^ (lr & 7)) * 8];
#pragma unroll
      for (int c = 0; c < 8; ++c) {
        const int rv = c * 16 + lr;
        bf16x8 vf = *(const bf16x8*)(VsB + rv * 128 + ((ks * 64 + lg * 16) ^ ((rv & 7) << 4)));
        o[0][c] = __builtin_amdgcn_mfma_f32_16x16x32_bf16(af0, vf, o[0][c], 0, 0, 0);
        o[1][c] = __builtin_amdgcn_mfma_f32_16x16x32_bf16(af1, vf, o[1][c], 0, 0, 0);
      }
    }
    __builtin_amdgcn_s_setprio(0);
    VM(0);
    BARRIER_();
    cur ^= 1;
  }
#undef STAGE_KV
#pragma unroll
  for (int f = 0; f < 2; ++f) {
    float lrj[4];
#pragma unroll
    for (int j = 0; j < 4; ++j) lrj[j] = __shfl(lrun[f], lg * 4 + j);
#pragma unroll
    for (int c = 0; c < 8; ++c)
#pragma unroll
      for (int j = 0; j < 4; ++j) {
        const int srow = q0 + wid * 32 + f * 16 + lg * 4 + j;
        const float v = o[f][c][j] / lrj[j];
        Og[((size_t)b * S_ + srow) * (NH * HD) + h * HD + c * 16 + lr] = f2b(v);
      }
  }
}

extern "C" void kernel_launch(void* const* d_in, const int* in_sizes, int n_in,
                              void* d_out, int out_size, void* d_ws, size_t ws_size,
                              hipStream_t stream) {
  const float* x = (const float*)d_in[0];
  const float* fc = (const float*)d_in[1];
  const float* fs = (const float*)d_in[2];
  // d_in[3] positions (identity), d_in[4] mask (pure causal: WINDOW>=SEQ) -- analytic
  const float* wq = (const float*)d_in[5];
  const float* wk = (const float*)d_in[6];
  const float* wv = (const float*)d_in[7];
  const float* wo = (const float*)d_in[8];
  char* ws = (char*)d_ws;
  const size_t MB = 1024 * 1024;
  u16* xb = (u16*)(ws);                  // 32 MB  [4096][4096], dead after QKV gemm
  u16* wqkvb = (u16*)(ws + 32 * MB);     // 48 MB  [6144][4096], dead after QKV gemm
  u16* wob = (u16*)(ws + 80 * MB);       // 32 MB, live until O-proj
  u16* Q = (u16*)(ws + 112 * MB);        // 32 MB  [B][NH][S][HD]
  u16* Kr = (u16*)(ws + 144 * MB);       // 8 MB   [B][NKV][S][HD]
  u16* Vt = (u16*)(ws + 152 * MB);       // 8 MB   [B][NKV][HD][S]
  float2* cs = (float2*)(ws + 160 * MB); // 1 MB   [S][64] (cos,sin)
  u16* attn = xb;                        // 32 MB, reuses xb after QKV gemm
  float* out = (float*)d_out;

  // casts + cs table: 57344 + 512 blocks
  k_cast_all<<<57856, 256, 0, stream>>>(x, wq, wk, wv, wo, fc, fs, xb, wqkvb, wob, cs);

  // fused QKV projection + RoPE + layout: 32x32 tiles of 128x192, 1024 blocks = 2 rounds @ 2/CU
  k_gemm192nf<4096, 32, 32, 8, 16><<<1024, 256, 0, stream>>>(xb, wqkvb, Q, Kr, Vt, cs);

  k_attn<<<1024, 256, 0, stream>>>(Q, Kr, Vt, attn);

  // O projection: 32x32 tiles of 128x128, 1024 blocks = 2 rounds @ 2/CU
  k_gemm256<4096, 4096, 32, 32, 8, 16><<<1024, 256, 0, stream>>>(attn, wob, out);
}

// Round 14
// 453.802 us; speedup vs baseline: 1.0495x; 1.0495x over previous
//
#include <hip/hip_runtime.h>
#include <hip/hip_bf16.h>

typedef unsigned short u16;
typedef unsigned int u32;
typedef unsigned long long u64;
typedef __bf16 bf16x8 __attribute__((ext_vector_type(8)));
typedef float f32x4 __attribute__((ext_vector_type(4)));
typedef u16 u16x8 __attribute__((ext_vector_type(8)));

#define B_ 2
#define S_ 2048
#define NH 32
#define NKV 8
#define HD 128
#define DIM_ 4096
#define NQKV 6144  // fused projection width: 4096 Q + 1024 K + 1024 V

__device__ inline u16 f2b(float f) {
  u32 u = __builtin_bit_cast(u32, f);
  u = (u + 0x7fffu + ((u >> 16) & 1u)) >> 16;
  return (u16)u;
}
__device__ inline float b2f(u16 b) {
  u32 u = ((u32)b) << 16;
  return __builtin_bit_cast(float, u);
}

__device__ inline void gload_lds16(const u16* g, u16* l) {
  __builtin_amdgcn_global_load_lds((__attribute__((address_space(1))) void*)g,
                                   (__attribute__((address_space(3))) void*)l, 16, 0, 0);
}

#define BARRIER_()                      \
  __builtin_amdgcn_sched_barrier(0);    \
  __builtin_amdgcn_s_barrier();         \
  __builtin_amdgcn_sched_barrier(0)

#define VM(N) asm volatile("s_waitcnt vmcnt(" #N ")" ::: "memory")
#define NOP_ ((void)0)

// ------- merged f32 -> bf16 cast (5 tensors) + (cos,sin) float2 table build -------
__global__ __launch_bounds__(256) void k_cast_all(const float* __restrict__ x,
                                                  const float* __restrict__ wq,
                                                  const float* __restrict__ wk,
                                                  const float* __restrict__ wv,
                                                  const float* __restrict__ wo,
                                                  const float* __restrict__ cosb,
                                                  const float* __restrict__ sinb,
                                                  u16* __restrict__ xb,
                                                  u16* __restrict__ wqkvb,
                                                  u16* __restrict__ wob,
                                                  float2* __restrict__ cs) {
  int i = blockIdx.x * 256 + threadIdx.x;
  if (i >= 14680064) {  // cs table: 2048*64 entries
    const int idx = i - 14680064;
    cs[idx] = make_float2(cosb[idx], sinb[idx]);
    return;
  }
  const float* s;
  u16* d;
  int j;
  if (i < 4194304) { s = x; d = xb; j = i; }
  else if (i < 8388608) { s = wq; d = wqkvb; j = i - 4194304; }
  else if (i < 9437184) { s = wk; d = wqkvb + (size_t)4096 * 4096; j = i - 8388608; }
  else if (i < 10485760) { s = wv; d = wqkvb + (size_t)5120 * 4096; j = i - 9437184; }
  else { s = wo; d = wob; j = i - 10485760; }
  const float4 v = ((const float4*)s)[j];
  u32 lo = (u32)f2b(v.x) | ((u32)f2b(v.y) << 16);
  u32 hi = (u32)f2b(v.z) | ((u32)f2b(v.w) << 16);
  ((u32*)d)[(size_t)j * 2] = lo;
  ((u32*)d)[(size_t)j * 2 + 1] = hi;
}

// ========== 256x192 QKV GEMM, ONE barrier per K-tile, fused RoPE/layout ==========
template <int K, int MT, int NT, int CM, int CN>
__global__ __launch_bounds__(512, 2) void k_gemm192nf(const u16* __restrict__ A,
                                                      const u16* __restrict__ Bm,
                                                      u16* __restrict__ Q,
                                                      u16* __restrict__ Kr,
                                                      u16* __restrict__ Vt,
                                                      const float2* __restrict__ cs) {
  __shared__ __align__(16) u16 lds[2][7][64 * 64];  // 112KB
  const int bid = blockIdx.x;
  const int xcd = bid & 7, slot = bid >> 3;
  constexpr int XM = MT / CM;
  const int xm = xcd % XM, xn = xcd / XM;
  const int m0 = (xm * CM + slot % CM) * 256;
  const int n0 = (xn * CN + slot / CM) * 192;
  const int tid = threadIdx.x, w = tid >> 6, lane = tid & 63;
  const int wm = w >> 2, wn = w & 3;
  const int lr = lane & 15, lg = lane >> 4;
  const int lrow8 = lane >> 3;
  const int gcol = ((lane & 7) ^ lrow8) * 8;  // pre-swizzled source k-col (u16)
  f32x4 acc[8][3] = {};
  const u16* gsrc[7];
#pragma unroll
  for (int g = 0; g < 4; ++g) gsrc[g] = A + (size_t)(m0 + g * 64) * K;
#pragma unroll
  for (int g = 0; g < 3; ++g) gsrc[4 + g] = Bm + (size_t)(n0 + g * 64) * K;

#define SG(DST, G, KN) \
  gload_lds16(gsrc[G] + (size_t)(w * 8 + lrow8) * K + (KN) + gcol, &lds[DST][G][w * 512])

#define TILE1B(BB, HS, KN, LAST)                                                          \
  {                                                                                       \
    if (HS) {                                                                             \
      SG(BB ^ 1, 0, KN); SG(BB ^ 1, 1, KN); SG(BB ^ 1, 2, KN); SG(BB ^ 1, 3, KN);         \
      SG(BB ^ 1, 4, KN); SG(BB ^ 1, 5, KN); SG(BB ^ 1, 6, KN);                            \
    }                                                                                     \
    bf16x8 af[8][2];                                                                      \
    _Pragma("unroll") for (int f = 0; f < 8; ++f)                                         \
      _Pragma("unroll") for (int ks = 0; ks < 2; ++ks)                                    \
        af[f][ks] = *(const bf16x8*)&lds[BB][wm * 2 + (f >> 2)]                           \
            [((f & 3) * 16 + lr) * 64 + ((ks * 4 + lg) ^ (lr & 7)) * 8];                  \
    __builtin_amdgcn_s_setprio(1);                                                        \
    _Pragma("unroll") for (int p = 0; p < 3; ++p) {                                       \
      bf16x8 bfr[2];                                                                      \
      _Pragma("unroll") for (int ks = 0; ks < 2; ++ks)                                    \
        bfr[ks] = *(const bf16x8*)&lds[BB][4 + p]                                         \
            [(wn * 16 + lr) * 64 + ((ks * 4 + lg) ^ (lr & 7)) * 8];                       \
      _Pragma("unroll") for (int f = 0; f < 8; ++f)                                       \
        _Pragma("unroll") for (int ks = 0; ks < 2; ++ks)                                  \
          acc[f][p] = __builtin_amdgcn_mfma_f32_16x16x32_bf16(af[f][ks], bfr[ks],         \
                                                              acc[f][p], 0, 0, 0);       \
    }                                                                                     \
    __builtin_amdgcn_s_setprio(0);                                                        \
    if (LAST) { VM(0); BARRIER_(); }                                                      \
  }

  // prologue: stage tile 0 -> buf0, full drain
#pragma unroll
  for (int g = 0; g < 7; ++g) SG(0, g, 0);
  VM(0);
  BARRIER_();

  for (int tt = 0; tt < (K / 64) - 2; tt += 2) {
    TILE1B(0, 1, (tt + 1) * 64, 1);
    TILE1B(1, 1, (tt + 2) * 64, 1);
  }
  TILE1B(0, 1, (K / 64 - 1) * 64, 1);  // stages final tile
  TILE1B(1, 0, 0, 0);                  // final tile: pure compute, no sync
#undef TILE1B
#undef SG

  // -------- fused RoPE + layout epilogue --------
#pragma unroll
  for (int mf = 0; mf < 8; ++mf) {
    const int r = m0 + wm * 128 + mf * 16 + lg * 4;
    const int b = r >> 11;   // rows r..r+3 share b (4 | 2048)
    const int s = r & 2047;
#pragma unroll
    for (int p = 0; p < 3; ++p) {
      const int gb = n0 + p * 64;          // group base, multiple of 64
      const int cc = gb + wn * 16 + lr;
      if (gb < 5120) {  // Q or K: RoPE + [B][H][S][D]
        const bool isQ = gb < 4096;
        const int cx = isQ ? cc : cc - 4096;
        const int h = cx >> 7, d = cx & 127;
        u16* dst = (isQ ? Q : Kr) +
                   (((size_t)b * (isQ ? NH : NKV) + h) * S_ + s) * HD + d;
        const float sgn = (lr & 1) ? 1.f : -1.f;
#pragma unroll
        for (int j = 0; j < 4; ++j) {
          const float val = acc[mf][p][j];
          const float par = __shfl_xor(val, 1);
          const float2 csv = cs[(s + j) * 64 + (d >> 1)];
          dst[(size_t)j * HD] = f2b(val * csv.x + sgn * par * csv.y);
        }
      } else {  // V: direct transpose [B][NKV][HD][S], 4 rows packed u64
        const int cv = cc - 5120;
        const int hv = cv >> 7, dv = cv & 127;
        u64 pk = 0;
#pragma unroll
        for (int j = 0; j < 4; ++j)
          pk |= (u64)f2b(acc[mf][p][j]) << (16 * j);
        *(u64*)&Vt[(((size_t)b * NKV + hv) * HD + dv) * S_ + s] = pk;
      }
    }
  }
}

// ========== 256x256 O-projection GEMM (f32 out), ONE barrier per K-tile ==========
template <int N, int K, int MT, int NT, int CM, int CN>
__global__ __launch_bounds__(512, 2) void k_gemm256(const u16* __restrict__ A,
                                                    const u16* __restrict__ Bm,
                                                    float* __restrict__ Cout) {
  __shared__ __align__(16) u16 lds[2][8][64 * 64];  // 128KB
  const int bid = blockIdx.x;
  const int xcd = bid & 7, slot = bid >> 3;
  constexpr int XM = MT / CM;
  const int xm = xcd % XM, xn = xcd / XM;
  const int m0 = (xm * CM + slot % CM) * 256;
  const int n0 = (xn * CN + slot / CM) * 256;
  const int tid = threadIdx.x, w = tid >> 6, lane = tid & 63;
  const int wm = w >> 2, wn = w & 3;
  const int lr = lane & 15, lg = lane >> 4;
  const int lrow8 = lane >> 3;
  const int gcol = ((lane & 7) ^ lrow8) * 8;
  f32x4 acc[8][4] = {};
  const u16* gsrc[8];
#pragma unroll
  for (int g = 0; g < 4; ++g) gsrc[g] = A + (size_t)(m0 + g * 64) * K;
#pragma unroll
  for (int g = 0; g < 4; ++g) gsrc[4 + g] = Bm + (size_t)(n0 + g * 64) * K;

#define SG(DST, G, KN) \
  gload_lds16(gsrc[G] + (size_t)(w * 8 + lrow8) * K + (KN) + gcol, &lds[DST][G][w * 512])

#define TILE1B(BB, HS, KN, LAST)                                                          \
  {                                                                                       \
    if (HS) {                                                                             \
      SG(BB ^ 1, 0, KN); SG(BB ^ 1, 1, KN); SG(BB ^ 1, 2, KN); SG(BB ^ 1, 3, KN);         \
      SG(BB ^ 1, 4, KN); SG(BB ^ 1, 5, KN); SG(BB ^ 1, 6, KN); SG(BB ^ 1, 7, KN);         \
    }                                                                                     \
    bf16x8 bfr[4][2];                                                                     \
    _Pragma("unroll") for (int nf = 0; nf < 4; ++nf) {                                    \
      const int rowB = wn * 64 + nf * 16 + lr;                                            \
      _Pragma("unroll") for (int ks = 0; ks < 2; ++ks)                                    \
        bfr[nf][ks] = *(const bf16x8*)&lds[BB][4 + (rowB >> 6)]                           \
            [(rowB & 63) * 64 + ((ks * 4 + lg) ^ (lr & 7)) * 8];                          \
    }                                                                                     \
    __builtin_amdgcn_s_setprio(1);                                                        \
    _Pragma("unroll") for (int p = 0; p < 4; ++p) {                                       \
      bf16x8 af[2][2];                                                                    \
      _Pragma("unroll") for (int mi = 0; mi < 2; ++mi)                                    \
        _Pragma("unroll") for (int ks = 0; ks < 2; ++ks)                                  \
          af[mi][ks] = *(const bf16x8*)&lds[BB][wm * 2 + ((p * 2 + mi) >> 2)]             \
              [(((p * 2 + mi) & 3) * 16 + lr) * 64 + ((ks * 4 + lg) ^ (lr & 7)) * 8];     \
      _Pragma("unroll") for (int mi = 0; mi < 2; ++mi)                                    \
        _Pragma("unroll") for (int nf = 0; nf < 4; ++nf)                                  \
          _Pragma("unroll") for (int ks = 0; ks < 2; ++ks)                                \
            acc[p * 2 + mi][nf] = __builtin_amdgcn_mfma_f32_16x16x32_bf16(                \
                af[mi][ks], bfr[nf][ks], acc[p * 2 + mi][nf], 0, 0, 0);                   \
    }                                                                                     \
    __builtin_amdgcn_s_setprio(0);                                                        \
    if (LAST) { VM(0); BARRIER_(); }                                                      \
  }

#pragma unroll
  for (int g = 0; g < 8; ++g) SG(0, g, 0);
  VM(0);
  BARRIER_();

  for (int tt = 0; tt < (K / 64) - 2; tt += 2) {
    TILE1B(0, 1, (tt + 1) * 64, 1);
    TILE1B(1, 1, (tt + 2) * 64, 1);
  }
  TILE1B(0, 1, (K / 64 - 1) * 64, 1);
  TILE1B(1, 0, 0, 0);
#undef TILE1B
#undef SG

#pragma unroll
  for (int mf = 0; mf < 8; ++mf) {
    const int r = m0 + wm * 128 + mf * 16 + lg * 4;
#pragma unroll
    for (int nf = 0; nf < 4; ++nf) {
      const int cc = n0 + wn * 64 + nf * 16 + lr;
#pragma unroll
      for (int j = 0; j < 4; ++j)
        Cout[(size_t)(r + j) * N + cc] = acc[mf][nf][j];
    }
  }
}

// ---------------- Flash attention, causal, GQA rep=4, paired persistent blocks ----------------
// Each block handles TWO complementary q-tiles (qt0 and 15-qt0) of the same (b,kvh,h):
// uniform 34 KV-tiles/block, grid 512 = exactly 1 round at 2 blocks/CU, zero tail.
// 4 waves x 32 q-rows (2 q-frags); swapped QK^T; T5 setprio; T13 defer-max.
__global__ __launch_bounds__(256, 2) void k_attn(const u16* __restrict__ Qg,
                                                 const u16* __restrict__ Kg,
                                                 const u16* __restrict__ Vtg,
                                                 u16* __restrict__ Og) {
  __shared__ __align__(16) u16 Ks[2][64 * 128];   // 2 x 16KB, rows 256B, XOR-swizzled
  __shared__ __align__(16) u16 Vs[2][128 * 64];   // 2 x 16KB, rows 128B, XOR-swizzled
  __shared__ __align__(16) u16 Ps[4][2][16][64];  // 16KB, per-(wave,frag), chunk-swizzled
  const int bid = blockIdx.x;
  const int xcd = bid & 7, slot = bid >> 3;     // grid 512: 8 xcd x 64
  const int g = xcd * 2 + (slot >> 5);          // (b,kvh) group 0..15
  const int r_ = slot & 31;
  const int hq = r_ & 3;
  const int qt0 = r_ >> 2;                      // 0..7; units: qt0 and 15-qt0
  const int b = g >> 3, kvh = g & 7, h = kvh * 4 + hq;
  const int tid = threadIdx.x, wid = tid >> 6, lane = tid & 63;
  const int lr = lane & 15, lg = lane >> 4;
  const u16* kb2 = Kg + ((size_t)b * NKV + kvh) * (size_t)S_ * HD;
  const u16* vb2 = Vtg + ((size_t)b * NKV + kvh) * (size_t)HD * S_;
  const int pbase = lr * 16 + (lg & 1);

#define STAGE_KV(BUF, T)                                                               \
  {                                                                                    \
    _Pragma("unroll") for (int i = 0; i < 4; ++i) {                                    \
      const int kr = wid * 16 + i * 4 + lg;                                            \
      gload_lds16(kb2 + (size_t)((T) * 64 + kr) * HD + ((lane & 15) ^ (kr & 7)) * 8,   \
                  &Ks[BUF][(wid * 16 + i * 4) * 128]);                                 \
    }                                                                                  \
    _Pragma("unroll") for (int i = 0; i < 4; ++i) {                                    \
      const int dr = wid * 32 + i * 8 + (lane >> 3);                                   \
      gload_lds16(vb2 + (size_t)dr * S_ + (T) * 64 + ((lane & 7) ^ (dr & 7)) * 8,      \
                  &Vs[BUF][(wid * 32 + i * 8) * 64]);                                  \
    }                                                                                  \
  }

  for (int unit = 0; unit < 2; ++unit) {
    const int qt = unit ? (15 - qt0) : qt0;
    const int q0 = qt * 128;
    bf16x8 qf[2][4];
#pragma unroll
    for (int f = 0; f < 2; ++f) {
      const u16* qp =
          Qg + (((size_t)b * NH + h) * S_ + q0 + wid * 32 + f * 16 + lr) * HD + lg * 8;
#pragma unroll
      for (int ks = 0; ks < 4; ++ks) qf[f][ks] = *(const bf16x8*)(qp + ks * 32);
    }
    f32x4 o[2][8] = {};
    float mrun[2] = {-1e30f, -1e30f}, lrun[2] = {0.f, 0.f};
    const int nt = 2 * qt + 2;
    STAGE_KV(0, 0);
    VM(0);
    BARRIER_();
    int cur = 0;
    const int qrow0 = q0 + wid * 32 + lr;
    for (int t = 0; t < nt; ++t) {
      if (t < nt - 1) STAGE_KV(cur ^ 1, t + 1);
      __builtin_amdgcn_sched_barrier(0);
      const char* KsB = (const char*)&Ks[cur][0];
      const char* VsB = (const char*)&Vs[cur][0];
      f32x4 s[2][4] = {};
      __builtin_amdgcn_s_setprio(1);
#pragma unroll
      for (int ks = 0; ks < 4; ++ks) {
        bf16x8 kf4[4];
#pragma unroll
        for (int n = 0; n < 4; ++n) {
          const int rr = n * 16 + lr;
          kf4[n] = *(const bf16x8*)(KsB + rr * 256 + ((ks * 64 + lg * 16) ^ ((rr & 7) << 4)));
        }
#pragma unroll
        for (int f = 0; f < 2; ++f)
#pragma unroll
          for (int n = 0; n < 4; ++n)
            s[f][n] = __builtin_amdgcn_mfma_f32_16x16x32_bf16(kf4[n], qf[f][ks], s[f][n], 0, 0, 0);
      }
      __builtin_amdgcn_s_setprio(0);
      const float scale = 0.08838834764831845f;
      float pm[2] = {-1e30f, -1e30f};
      const int kvb = t * 64 + lg * 4;
#pragma unroll
      for (int f = 0; f < 2; ++f) {
        const bool diag = (t * 64 + 63 > q0 + wid * 32 + f * 16);
#pragma unroll
        for (int n = 0; n < 4; ++n)
#pragma unroll
          for (int j = 0; j < 4; ++j) {
            float v = s[f][n][j] * scale;
            if (diag && (kvb + n * 16 + j > qrow0 + f * 16)) v = -1e30f;  // causal
            s[f][n][j] = v;
            pm[f] = fmaxf(pm[f], v);
          }
      }
#pragma unroll
      for (int f = 0; f < 2; ++f) {
        pm[f] = fmaxf(pm[f], __shfl_xor(pm[f], 16));
        pm[f] = fmaxf(pm[f], __shfl_xor(pm[f], 32));
      }
      float al[2] = {1.f, 1.f};
      float mt[2] = {mrun[0], mrun[1]};
      if (!__all(pm[0] <= mrun[0] + 8.f && pm[1] <= mrun[1] + 8.f)) {
#pragma unroll
        for (int f = 0; f < 2; ++f) {
          mt[f] = fmaxf(mrun[f], pm[f]);
          al[f] = __expf(mrun[f] - mt[f]);
          mrun[f] = mt[f];
          float alj[4];
#pragma unroll
          for (int j = 0; j < 4; ++j) alj[j] = __shfl(al[f], lg * 4 + j);
#pragma unroll
          for (int c = 0; c < 8; ++c)
#pragma unroll
            for (int j = 0; j < 4; ++j) o[f][c][j] *= alj[j];
        }
      }
      float ls[2] = {0.f, 0.f};
#pragma unroll
      for (int f = 0; f < 2; ++f) {
        u64* Ps64 = (u64*)&Ps[wid][f][0][0];
#pragma unroll
        for (int n = 0; n < 4; ++n) {
          const float p0 = __expf(s[f][n][0] - mt[f]), p1 = __expf(s[f][n][1] - mt[f]);
          const float p2 = __expf(s[f][n][2] - mt[f]), p3 = __expf(s[f][n][3] - mt[f]);
          ls[f] += (p0 + p1) + (p2 + p3);
          const u32 w0 = (u32)f2b(p0) | ((u32)f2b(p1) << 16);
          const u32 w1 = (u32)f2b(p2) | ((u32)f2b(p3) << 16);
          Ps64[pbase + (((n * 2 + (lg >> 1)) ^ (lr & 7)) << 1)] = (u64)w0 | ((u64)w1 << 32);
        }
      }
#pragma unroll
      for (int f = 0; f < 2; ++f) {
        ls[f] += __shfl_xor(ls[f], 16);
        ls[f] += __shfl_xor(ls[f], 32);
        lrun[f] = lrun[f] * al[f] + ls[f];
      }
      asm volatile("s_waitcnt lgkmcnt(0)" ::: "memory");
      __builtin_amdgcn_sched_barrier(0);
      __builtin_amdgcn_s_setprio(1);
#pragma unroll
      for (int ks = 0; ks < 2; ++ks) {
        bf16x8 af0 = *(const bf16x8*)&Ps[wid][0][lr][((ks * 4 + lg) ^ (lr & 7)) * 8];
        bf16x8 af1 = *(const bf16x8*)&Ps[wid][1][lr][((ks * 4 + lg) ^ (lr & 7)) * 8];
#pragma unroll
        for (int c = 0; c < 8; ++c) {
          const int rv = c * 16 + lr;
          bf16x8 vf = *(const bf16x8*)(VsB + rv * 128 + ((ks * 64 + lg * 16) ^ ((rv & 7) << 4)));
          o[0][c] = __builtin_amdgcn_mfma_f32_16x16x32_bf16(af0, vf, o[0][c], 0, 0, 0);
          o[1][c] = __builtin_amdgcn_mfma_f32_16x16x32_bf16(af1, vf, o[1][c], 0, 0, 0);
        }
      }
      __builtin_amdgcn_s_setprio(0);
      VM(0);
      BARRIER_();
      cur ^= 1;
    }
#pragma unroll
    for (int f = 0; f < 2; ++f) {
      float lrj[4];
#pragma unroll
      for (int j = 0; j < 4; ++j) lrj[j] = __shfl(lrun[f], lg * 4 + j);
#pragma unroll
      for (int c = 0; c < 8; ++c)
#pragma unroll
        for (int j = 0; j < 4; ++j) {
          const int srow = q0 + wid * 32 + f * 16 + lg * 4 + j;
          const float v = o[f][c][j] / lrj[j];
          Og[((size_t)b * S_ + srow) * (NH * HD) + h * HD + c * 16 + lr] = f2b(v);
        }
    }
  }
#undef STAGE_KV
}

extern "C" void kernel_launch(void* const* d_in, const int* in_sizes, int n_in,
                              void* d_out, int out_size, void* d_ws, size_t ws_size,
                              hipStream_t stream) {
  const float* x = (const float*)d_in[0];
  const float* fc = (const float*)d_in[1];
  const float* fs = (const float*)d_in[2];
  // d_in[3] positions (identity), d_in[4] mask (pure causal: WINDOW>=SEQ) -- analytic
  const float* wq = (const float*)d_in[5];
  const float* wk = (const float*)d_in[6];
  const float* wv = (const float*)d_in[7];
  const float* wo = (const float*)d_in[8];
  char* ws = (char*)d_ws;
  const size_t MB = 1024 * 1024;
  u16* xb = (u16*)(ws);                  // 32 MB  [4096][4096], dead after QKV gemm
  u16* wqkvb = (u16*)(ws + 32 * MB);     // 48 MB  [6144][4096], dead after QKV gemm
  u16* wob = (u16*)(ws + 80 * MB);       // 32 MB, live until O-proj
  u16* Q = (u16*)(ws + 112 * MB);        // 32 MB  [B][NH][S][HD]
  u16* Kr = (u16*)(ws + 144 * MB);       // 8 MB   [B][NKV][S][HD]
  u16* Vt = (u16*)(ws + 152 * MB);       // 8 MB   [B][NKV][HD][S]
  float2* cs = (float2*)(ws + 160 * MB); // 1 MB   [S][64] (cos,sin)
  u16* attn = xb;                        // 32 MB, reuses xb after QKV gemm
  float* out = (float*)d_out;

  // casts + cs table: 57344 + 512 blocks
  k_cast_all<<<57856, 256, 0, stream>>>(x, wq, wk, wv, wo, fc, fs, xb, wqkvb, wob, cs);

  // fused QKV projection + RoPE + layout: 16x32 tiles of 256x192, 2 exact rounds
  k_gemm192nf<4096, 16, 32, 8, 8><<<512, 512, 0, stream>>>(xb, wqkvb, Q, Kr, Vt, cs);

  // attention: 512 paired persistent blocks = 1 exact round at 2 blocks/CU
  k_attn<<<512, 256, 0, stream>>>(Q, Kr, Vt, attn);

  // O projection: 16x16 tiles of 256^2, 256 blocks = 1 round
  k_gemm256<4096, 4096, 16, 16, 8, 4><<<256, 512, 0, stream>>>(attn, wob, out);
}